// Round 20
// baseline (368.747 us; speedup 1.0000x reference)
//
#include <hip/hip_runtime.h>
#include <hip/hip_bf16.h>

typedef short s16x8 __attribute__((ext_vector_type(8)));
typedef float f32x4 __attribute__((ext_vector_type(4)));
typedef unsigned short u16x8 __attribute__((ext_vector_type(8)));

__device__ __forceinline__ float bf2f(unsigned short u){
  union { unsigned int i; float f; } v; v.i = ((unsigned int)u) << 16; return v.f;
}
__device__ __forceinline__ unsigned short f2bf(float f){
  union { float f; unsigned int i; } v; v.f = f;
  unsigned int x = v.i;
  return (unsigned short)((x + 0x7fffu + ((x >> 16) & 1u)) >> 16);
}
__device__ __forceinline__ short f2bs(float f){
  union { __hip_bfloat16 h; short s; } u; u.h = __float2bfloat16(f); return u.s;
}
__device__ __forceinline__ s16x8 cvt8(f32x4 a, f32x4 b){
  s16x8 r;
  r[0]=f2bs(a[0]); r[1]=f2bs(a[1]); r[2]=f2bs(a[2]); r[3]=f2bs(a[3]);
  r[4]=f2bs(b[0]); r[5]=f2bs(b[1]); r[6]=f2bs(b[2]); r[7]=f2bs(b[3]);
  return r;
}

__device__ __forceinline__ void gload16(const void* g, void* l){
  __builtin_amdgcn_global_load_lds(
      (__attribute__((address_space(1))) void*)(g),
      (__attribute__((address_space(3))) void*)(l), 16, 0, 0);
}

// cast the 4 weight matrices (512x512 f32) to bf16 in one launch
__global__ __launch_bounds__(256) void cast_w(
    const float* __restrict__ w0, const float* __restrict__ w1,
    const float* __restrict__ w2, const float* __restrict__ w3,
    unsigned short* __restrict__ o0, unsigned short* __restrict__ o1,
    unsigned short* __restrict__ o2, unsigned short* __restrict__ o3)
{
  int g = blockIdx.x * 256 + threadIdx.x;
  int which = g >> 15;
  int off = (g & 32767) * 8;
  const float* src = which==0 ? w0 : which==1 ? w1 : which==2 ? w2 : w3;
  unsigned short* dst = which==0 ? o0 : which==1 ? o1 : which==2 ? o2 : o3;
  float4 a = *(const float4*)(src + off);
  float4 b = *(const float4*)(src + off + 4);
  u16x8 r;
  r[0]=f2bf(a.x); r[1]=f2bf(a.y); r[2]=f2bf(a.z); r[3]=f2bf(a.w);
  r[4]=f2bf(b.x); r[5]=f2bf(b.y); r[6]=f2bf(b.z); r[7]=f2bf(b.w);
  *(u16x8*)(dst + off) = r;
}

// Best-known engine (R13/R16): out[.][512] = (A_f32 @ B_bf16^T + bias)*scale
// BK=64, 2-slot dbuf, tile 128x256, 8 waves 2x4. One counted vmcnt per K-tile.
template<int OUT_MODE, int NT, int KT>
__global__ __launch_bounds__(512, 1) void gemm_k64(
    const float* __restrict__ A, const unsigned short* __restrict__ B,
    const float* __restrict__ bias, float scale, void* __restrict__ out_,
    int SA, int SB)
{
  __shared__ float          Af[2][128*64];
  __shared__ unsigned short Bf[2][256*64];

  const int nwg = gridDim.x;
  const int bid = blockIdx.x;
  const int wgid = (bid & 7) * (nwg >> 3) + (bid >> 3);

  const int t = threadIdx.x;
  const int wid = t >> 6, lane = t & 63;
  const int wm = wid >> 2, wn = wid & 3;
  const int rl = lane & 15, kg = lane >> 4;

  const int bn = wgid & 1;
  const int bmg = wgid >> 1;
  const float* Ab0 = A + (size_t)bmg * (NT*128) * SA;
  const unsigned short* Bb0 = B + (size_t)bn * 256 * SB;

  const int jrowA = wid*4 + (lane >> 4);
  const int aslot = lane & 15;
  const int jcolB = wid*8 + (lane >> 3);
  const int bslot = lane & 7;

  #define STAGE(T_) do{                                                        \
    const int st_ = (T_) & 1;                                                  \
    const int kt_ = (T_) & (KT-1);                                             \
    const int tau_ = (T_) / KT;                                                \
    const float* As_ = Ab0 + (size_t)tau_*128*SA + kt_*64;                     \
    const unsigned short* Bs_ = Bb0 + kt_*64;                                  \
    _Pragma("unroll")                                                          \
    for (int j = 0; j < 4; ++j){                                               \
      int ar = j*32 + jrowA;                                                   \
      gload16(As_ + (size_t)ar*SA + ((aslot ^ (ar&15)) << 2),                  \
              &Af[st_][(j*8 + wid)*256]);                                      \
      int bc = j*64 + jcolB;                                                   \
      gload16(Bs_ + (size_t)bc*SB + ((bslot ^ (bc&7)) << 3),                   \
              &Bf[st_][(j*8 + wid)*512]);                                      \
    }                                                                          \
  }while(0)

  #define READS(sl_, h_, af_, bw_) do{                                         \
    _Pragma("unroll")                                                          \
    for (int m = 0; m < 4; ++m){                                               \
      const int r_ = wm*64 + m*16 + rl;                                        \
      const int s0_ = (h_)*8 + kg*2;                                           \
      f32x4 x0 = *(const f32x4*)&Af[sl_][r_*64 + ((s0_     ^ (r_&15)) << 2)];  \
      f32x4 x1 = *(const f32x4*)&Af[sl_][r_*64 + (((s0_+1) ^ (r_&15)) << 2)];  \
      af_[m] = cvt8(x0, x1);                                                   \
    }                                                                          \
    _Pragma("unroll")                                                          \
    for (int n = 0; n < 4; ++n){                                               \
      const int c_ = wn*64 + n*16 + rl;                                        \
      const int sb_ = (h_)*4 + kg;                                             \
      bw_[n] = *(const s16x8*)&Bf[sl_][c_*64 + ((sb_ ^ (c_&7)) << 3)];         \
    }                                                                          \
  }while(0)

  #define MFMA16(af_, bw_) do{                                                 \
    __builtin_amdgcn_s_setprio(1);                                             \
    _Pragma("unroll")                                                          \
    for (int m = 0; m < 4; ++m)                                                \
      _Pragma("unroll")                                                        \
      for (int n = 0; n < 4; ++n)                                              \
        acc[m][n] = __builtin_amdgcn_mfma_f32_16x16x32_bf16(af_[m], bw_[n], acc[m][n], 0, 0, 0); \
    __builtin_amdgcn_s_setprio(0);                                             \
  }while(0)

  f32x4 acc[4][4];
  #pragma unroll
  for (int m=0;m<4;m++)
    #pragma unroll
    for (int n=0;n<4;n++) acc[m][n] = (f32x4){0.f,0.f,0.f,0.f};

  const int TT = NT * KT;
  STAGE(0); STAGE(1);
  asm volatile("s_waitcnt vmcnt(8)");
  __builtin_amdgcn_s_barrier();

  #pragma unroll 2
  for (int T = 0; T < TT; ++T){
    const int sl = T & 1;
    s16x8 af0[4], bw0[4], af1[4], bw1[4];

    READS(sl, 0, af0, bw0);
    MFMA16(af0, bw0);
    READS(sl, 1, af1, bw1);

    asm volatile("s_waitcnt lgkmcnt(0)");
    __builtin_amdgcn_s_barrier();

    if (T + 2 < TT) STAGE(T + 2);

    MFMA16(af1, bw1);

    if ((T & (KT-1)) == KT-1){
      const int tau = T / KT;
      #pragma unroll
      for (int n=0;n<4;n++){
        const int gcol = bn*256 + wn*64 + n*16 + rl;
        const float bv = bias[gcol];
        #pragma unroll
        for (int m=0;m<4;m++){
          #pragma unroll
          for (int r=0;r<4;r++){
            const int lrow = wm*64 + m*16 + kg*4 + r;
            const int grow = (bmg*NT + tau)*128 + lrow;
            float v = (acc[m][n][r] + bv) * scale;
            size_t idx = (size_t)grow * 512 + gcol;
            if (OUT_MODE == 1) ((unsigned short*)out_)[idx] = f2bf(v);
            else               ((float*)out_)[idx] = v;
          }
          acc[m][n] = (f32x4){0.f,0.f,0.f,0.f};
        }
      }
    }

    if (T + 2 < TT)      asm volatile("s_waitcnt vmcnt(8)");
    else if (T + 1 < TT) asm volatile("s_waitcnt vmcnt(0)");
    if (T + 1 < TT)      __builtin_amdgcn_s_barrier();
  }
  #undef STAGE
  #undef READS
  #undef MFMA16
}

// Fused K-proj -> scores (R19, proven): Kp never materialized; K bias cancels.
__global__ __launch_bounds__(512, 1) void gemm_ksc(
    const float* __restrict__ A, const unsigned short* __restrict__ B,
    const float* __restrict__ Qp, float* __restrict__ part)
{
  __shared__ float          Af[2][128*64];
  __shared__ unsigned short Bf[2][256*64];

  constexpr int NT = 8, KT = 8;
  const int nwg = gridDim.x;                    // 256
  const int bid = blockIdx.x;
  const int wgid = (bid & 7) * (nwg >> 3) + (bid >> 3);

  const int t = threadIdx.x;
  const int wid = t >> 6, lane = t & 63;
  const int wm = wid >> 2, wn = wid & 3;
  const int rl = lane & 15, kg = lane >> 4;

  const int bn = wgid & 1;
  const int bmg = wgid >> 1;
  const int b   = bmg >> 5;
  const int wwb = (bmg & 31) * 16;
  const float* Ab0 = A + (size_t)bmg * (NT*128) * 512;
  const unsigned short* Bb0 = B + (size_t)bn * 256 * 512;

  const int jrowA = wid*4 + (lane >> 4);
  const int aslot = lane & 15;
  const int jcolB = wid*8 + (lane >> 3);
  const int bslot = lane & 7;

  #define STAGE(T_) do{                                                        \
    const int st_ = (T_) & 1;                                                  \
    const int kt_ = (T_) & (KT-1);                                             \
    const int tau_ = (T_) / KT;                                                \
    const float* As_ = Ab0 + (size_t)tau_*128*512 + kt_*64;                    \
    const unsigned short* Bs_ = Bb0 + kt_*64;                                  \
    _Pragma("unroll")                                                          \
    for (int j = 0; j < 4; ++j){                                               \
      int ar = j*32 + jrowA;                                                   \
      gload16(As_ + (size_t)ar*512 + ((aslot ^ (ar&15)) << 2),                 \
              &Af[st_][(j*8 + wid)*256]);                                      \
      int bc = j*64 + jcolB;                                                   \
      gload16(Bs_ + (size_t)bc*512 + ((bslot ^ (bc&7)) << 3),                  \
              &Bf[st_][(j*8 + wid)*512]);                                      \
    }                                                                          \
  }while(0)

  #define READS(sl_, h_, af_, bw_) do{                                         \
    _Pragma("unroll")                                                          \
    for (int m = 0; m < 4; ++m){                                               \
      const int r_ = wm*64 + m*16 + rl;                                        \
      const int s0_ = (h_)*8 + kg*2;                                           \
      f32x4 x0 = *(const f32x4*)&Af[sl_][r_*64 + ((s0_     ^ (r_&15)) << 2)];  \
      f32x4 x1 = *(const f32x4*)&Af[sl_][r_*64 + (((s0_+1) ^ (r_&15)) << 2)];  \
      af_[m] = cvt8(x0, x1);                                                   \
    }                                                                          \
    _Pragma("unroll")                                                          \
    for (int n = 0; n < 4; ++n){                                               \
      const int c_ = wn*64 + n*16 + rl;                                        \
      const int sb_ = (h_)*4 + kg;                                             \
      bw_[n] = *(const s16x8*)&Bf[sl_][c_*64 + ((sb_ ^ (c_&7)) << 3)];         \
    }                                                                          \
  }while(0)

  #define MFMA16(af_, bw_) do{                                                 \
    __builtin_amdgcn_s_setprio(1);                                             \
    _Pragma("unroll")                                                          \
    for (int m = 0; m < 4; ++m)                                                \
      _Pragma("unroll")                                                        \
      for (int n = 0; n < 4; ++n)                                              \
        acc[m][n] = __builtin_amdgcn_mfma_f32_16x16x32_bf16(af_[m], bw_[n], acc[m][n], 0, 0, 0); \
    __builtin_amdgcn_s_setprio(0);                                             \
  }while(0)

  f32x4 acc[4][4], sc[4][4];
  #pragma unroll
  for (int m=0;m<4;m++)
    #pragma unroll
    for (int n=0;n<4;n++){
      acc[m][n] = (f32x4){0.f,0.f,0.f,0.f};
      sc[m][n]  = (f32x4){0.f,0.f,0.f,0.f};
    }
  float qp[4] = {0.f,0.f,0.f,0.f};

  const int TT = NT * KT;
  STAGE(0); STAGE(1);
  asm volatile("s_waitcnt vmcnt(8)");
  __builtin_amdgcn_s_barrier();

  #pragma unroll 2
  for (int T = 0; T < TT; ++T){
    const int sl = T & 1;
    s16x8 af0[4], bw0[4], af1[4], bw1[4];

    READS(sl, 0, af0, bw0);
    MFMA16(af0, bw0);
    READS(sl, 1, af1, bw1);

    asm volatile("s_waitcnt lgkmcnt(0)");
    __builtin_amdgcn_s_barrier();

    if (T + 2 < TT) STAGE(T + 2);

    if ((T & 7) == 0){
      const int tau = T >> 3;
      const int ww = wwb + tau*2 + wm;
      const float* qrow = Qp + ((size_t)(b*512 + ww))*512;
      #pragma unroll
      for (int n=0;n<4;n++) qp[n] = qrow[bn*256 + wn*64 + n*16 + rl];
    }

    MFMA16(af1, bw1);

    if ((T & 7) == 7){
      const int tau = T >> 3;
      #pragma unroll
      for (int n=0;n<4;n++)
        #pragma unroll
        for (int m=0;m<4;m++){
          #pragma unroll
          for (int r=0;r<4;r++) sc[m][n][r] += qp[n] * acc[m][n][r];
          acc[m][n] = (f32x4){0.f,0.f,0.f,0.f};
        }
      if (tau == 3 || tau == 7){
        const int half = tau >> 2;
        const int s = b*128 + (bmg & 31)*4 + half*2 + wm;
        #pragma unroll
        for (int n=0;n<4;n++){
          const int gcol = bn*256 + wn*64 + n*16 + rl;
          float* dst = part + ((size_t)s*512 + gcol)*64;
          #pragma unroll
          for (int m=0;m<4;m++){
            *(float4*)(dst + m*16 + kg*4) = *(float4*)&sc[m][n];
            sc[m][n] = (f32x4){0.f,0.f,0.f,0.f};
          }
        }
      }
    }

    if (T + 2 < TT)      asm volatile("s_waitcnt vmcnt(8)");
    else if (T + 1 < TT) asm volatile("s_waitcnt vmcnt(0)");
    if (T + 1 < TT)      __builtin_amdgcn_s_barrier();
  }
  #undef STAGE
  #undef READS
  #undef MFMA16
}

// Fused PV v3: BN=512 (V read once), split-K 16 -> 32 K-tiles/block.
// att_out[(w*4+b)][dd] += sum_k V[b,w,k] * (attn[b,dd,k>>9]*Wvb[dd,k&511]).
// All loads are register loads (no gload_lds) -> vm-waits compiler-automatic;
// 2-slot rotation needs ONE barrier per K-tile. LDS = 2x16K A + 2x64K B = 160 KiB.
__global__ __launch_bounds__(512, 1) void gemm_pv3(
    const float* __restrict__ V, const unsigned short* __restrict__ Wvb,
    const float* __restrict__ attn, float* __restrict__ att_out)
{
  __shared__ unsigned short Ah[2][128*64];   // 2 x 16 KB bf16
  __shared__ unsigned short Bh[2][512*64];   // 2 x 64 KB bf16

  const int nwg = gridDim.x;                 // 256
  const int bid = blockIdx.x;
  const int wgid = (bid & 7) * (nwg >> 3) + (bid >> 3);
  const int mt = wgid & 3;
  const int b  = (wgid >> 2) & 3;
  const int sk = wgid >> 4;                  // 0..15, 2048 k each

  const int t = threadIdx.x;
  const int wid = t >> 6, lane = t & 63;
  const int wm = wid >> 2, wn = wid & 3;     // 2x4 waves; wave tile 64 x 128
  const int rl = lane & 15, kg = lane >> 4;

  // A staging: row ar = t>>2, k-quarter ak = t&3 (16 f32 each)
  const int ar = t >> 2, ak = t & 3;
  const float* Arow = V + (size_t)b*512*32768 + (size_t)(mt*128 + ar)*32768
                        + (size_t)sk*2048 + ak*16;
  const int asw0 = ((ak*2    ) ^ (ar&7)) << 3;
  const int asw1 = ((ak*2 + 1) ^ (ar&7)) << 3;

  // B build: one dd-column per thread
  const int dd = t;
  const unsigned short* Wrow = Wvb + (size_t)dd*512;
  const float* attn_row = attn + (size_t)(b*512 + dd)*64 + sk*4;

  f32x4 pa[4];
  s16x8 wv[8];
  float at_;

  #define AISSUE(T_) do{ const float* p_ = Arow + (T_)*64;                   \
    pa[0]=*(const f32x4*)(p_);   pa[1]=*(const f32x4*)(p_+4);                \
    pa[2]=*(const f32x4*)(p_+8); pa[3]=*(const f32x4*)(p_+12); }while(0)

  #define AWRITE(T_) do{ const int s_=(T_)&1;                                \
    unsigned short* d_ = &Ah[s_][ar*64];                                     \
    *(s16x8*)(d_ + asw0) = cvt8(pa[0],pa[1]);                                \
    *(s16x8*)(d_ + asw1) = cvt8(pa[2],pa[3]); }while(0)

  #define BLOAD(T_) do{ const unsigned short* w_ = Wrow + ((T_)&7)*64;       \
    wv[0]=*(const s16x8*)(w_);    wv[1]=*(const s16x8*)(w_+8);               \
    wv[2]=*(const s16x8*)(w_+16); wv[3]=*(const s16x8*)(w_+24);              \
    wv[4]=*(const s16x8*)(w_+32); wv[5]=*(const s16x8*)(w_+40);              \
    wv[6]=*(const s16x8*)(w_+48); wv[7]=*(const s16x8*)(w_+56);              \
    at_ = attn_row[(T_)>>3]; }while(0)

  #define BWRITE(T_) do{ const int s_=(T_)&1;                                \
    unsigned short* d_ = &Bh[s_][dd*64];                                     \
    _Pragma("unroll") for (int q=0;q<8;++q){ s16x8 o8;                       \
      _Pragma("unroll") for (int j=0;j<8;++j)                                \
        o8[j] = f2bs(bf2f((unsigned short)wv[q][j]) * at_);                  \
      *(s16x8*)(d_ + ((q ^ (dd&7)) << 3)) = o8; } }while(0)

  #define READS(sl_, h_) do{                                                 \
    _Pragma("unroll") for (int m=0;m<4;++m){                                 \
      const int r_ = wm*64 + m*16 + rl;                                      \
      af[m] = *(const s16x8*)&Ah[sl_][r_*64 + ((((h_)*4+kg) ^ (r_&7))<<3)];  \
    }                                                                        \
    _Pragma("unroll") for (int n=0;n<8;++n){                                 \
      const int c_ = wn*128 + n*16 + rl;                                     \
      bw[n] = *(const s16x8*)&Bh[sl_][c_*64 + ((((h_)*4+kg) ^ (c_&7))<<3)];  \
    } }while(0)

  #define MFMA32() do{                                                       \
    __builtin_amdgcn_s_setprio(1);                                           \
    _Pragma("unroll") for (int m=0;m<4;++m)                                  \
      _Pragma("unroll") for (int n=0;n<8;++n)                                \
        acc[m][n] = __builtin_amdgcn_mfma_f32_16x16x32_bf16(af[m], bw[n], acc[m][n], 0, 0, 0); \
    __builtin_amdgcn_s_setprio(0);                                           \
  }while(0)

  f32x4 acc[4][8];
  #pragma unroll
  for (int m=0;m<4;m++)
    #pragma unroll
    for (int n=0;n<8;n++) acc[m][n] = (f32x4){0.f,0.f,0.f,0.f};

  // prologue: tile 0 written to slot 0; tile 1 loads in flight
  AISSUE(0); BLOAD(0);
  AWRITE(0); BWRITE(0);
  AISSUE(1); BLOAD(1);
  asm volatile("s_waitcnt lgkmcnt(0)");
  __builtin_amdgcn_s_barrier();

  for (int T = 0; T < 32; ++T){
    const int sl = T & 1;
    s16x8 af[4], bw[8];

    READS(sl, 0);
    MFMA32();
    READS(sl, 1);

    if (T + 1 < 32){ AWRITE(T + 1); BWRITE(T + 1); }  // slot sl^1; old readers drained
    if (T + 2 < 32){ AISSUE(T + 2); BLOAD(T + 2); }

    MFMA32();

    if (T == 31){
      #pragma unroll
      for (int n=0;n<8;n++){
        const int gcol = wn*128 + n*16 + rl;
        #pragma unroll
        for (int m=0;m<4;m++)
          #pragma unroll
          for (int r=0;r<4;r++){
            const int w_ = mt*128 + wm*64 + m*16 + kg*4 + r;
            atomicAdd(&att_out[(size_t)(w_*4 + b)*512 + gcol], acc[m][n][r]);
          }
      }
    }

    if (T + 1 < 32){
      asm volatile("s_waitcnt lgkmcnt(0)");   // my reads + ds_writes drained
      __builtin_amdgcn_s_barrier();
    }
  }
  #undef AISSUE
  #undef AWRITE
  #undef BLOAD
  #undef BWRITE
  #undef READS
  #undef MFMA32
}

// softmax over m (reducing 128 slabs/row) + fused att_out bias-init
__global__ __launch_bounds__(256) void softmax_kernel(
    const float* __restrict__ part, float* __restrict__ attn,
    const float* __restrict__ bv, float* __restrict__ att_out)
{
  const int row = blockIdx.x*4 + (threadIdx.x >> 6);  // b*512+dd, 0..2047
  const int m = threadIdx.x & 63;
  const int b = row >> 9, dd = row & 511;
  float v = 0.f;
  #pragma unroll 8
  for (int j = 0; j < 128; ++j)
    v += part[((size_t)(b*128 + j)*512 + dd)*64 + m];
  float mx = v;
  #pragma unroll
  for (int o=32;o>=1;o>>=1) mx = fmaxf(mx, __shfl_xor(mx, o));
  float e = __expf(v - mx);
  float s = e;
  #pragma unroll
  for (int o=32;o>=1;o>>=1) s += __shfl_xor(s, o);
  attn[(size_t)row*64 + m] = e / s;

  const int base = blockIdx.x*256 + threadIdx.x;
  #pragma unroll
  for (int i=0;i<8;i++){
    int el = base + i*131072;
    att_out[el] = bv[el & 511];
  }
}

extern "C" void kernel_launch(void* const* d_in, const int* in_sizes, int n_in,
                              void* d_out, int out_size, void* d_ws, size_t ws_size,
                              hipStream_t stream) {
  const float* Q  = (const float*)d_in[0];
  const float* K  = (const float*)d_in[1];
  const float* V  = (const float*)d_in[2];
  const float* Wq = (const float*)d_in[3];
  const float* bq = (const float*)d_in[4];
  const float* Wk = (const float*)d_in[5];
  const float* bk = (const float*)d_in[6];
  const float* Wv = (const float*)d_in[7];
  const float* bv = (const float*)d_in[8];
  const float* Wp = (const float*)d_in[9];
  const float* bp = (const float*)d_in[10];
  float* out = (float*)d_out;
  (void)bk;  // K bias cancels in softmax

  char* ws = (char*)d_ws;
  float* Qp       = (float*)(ws);                       // 4 MiB
  float* att_out  = (float*)(ws + ((size_t)4<<20));     // 4 MiB
  float* attn     = (float*)(ws + ((size_t)8<<20));     // 0.5 MiB
  unsigned short* Wqb = (unsigned short*)(ws + ((size_t)9<<20));
  unsigned short* Wkb = Wqb + 262144;
  unsigned short* Wvb = Wkb + 262144;
  unsigned short* Wpb = Wvb + 262144;                   // 2 MiB total
  float* part     = (float*)(ws + ((size_t)11<<20));    // 512x512x64 f32 = 67 MiB

  const float qscale = 0.044194173824159223f;  // 1/sqrt(512)

  cast_w<<<512, 256, 0, stream>>>(Wq, Wk, Wv, Wp, Wqb, Wkb, Wvb, Wpb);

  // Q projection (+bias, /sqrt(d)) -> f32
  gemm_k64<0,1,8><<<32, 512, 0, stream>>>(Q, Wqb, bq, qscale, Qp, 512, 512);
  // fused K-projection -> score partials
  gemm_ksc<<<256, 512, 0, stream>>>(K, Wkb, Qp, part);
  // softmax (128-slab reduce) + att_out bias-init
  softmax_kernel<<<512, 256, 0, stream>>>(part, attn, bv, att_out);
  // fused PV v3: att_out += V @ (attn x Wvb)^T  (V read once, 32 tiles/CU)
  gemm_pv3<<<256, 512, 0, stream>>>(V, Wvb, attn, att_out);
  // output projection -> d_out
  gemm_k64<0,1,8><<<32, 512, 0, stream>>>(att_out, Wpb, bp, 1.f, out, 512, 512);
}

// Round 21
// 344.317 us; speedup vs baseline: 1.0710x; 1.0710x over previous
//
#include <hip/hip_runtime.h>
#include <hip/hip_bf16.h>

typedef short s16x8 __attribute__((ext_vector_type(8)));
typedef float f32x4 __attribute__((ext_vector_type(4)));
typedef unsigned short u16x8 __attribute__((ext_vector_type(8)));

__device__ __forceinline__ float bf2f(unsigned short u){
  union { unsigned int i; float f; } v; v.i = ((unsigned int)u) << 16; return v.f;
}
__device__ __forceinline__ unsigned short f2bf(float f){
  union { float f; unsigned int i; } v; v.f = f;
  unsigned int x = v.i;
  return (unsigned short)((x + 0x7fffu + ((x >> 16) & 1u)) >> 16);
}
__device__ __forceinline__ short f2bs(float f){
  union { __hip_bfloat16 h; short s; } u; u.h = __float2bfloat16(f); return u.s;
}
__device__ __forceinline__ s16x8 cvt8(f32x4 a, f32x4 b){
  s16x8 r;
  r[0]=f2bs(a[0]); r[1]=f2bs(a[1]); r[2]=f2bs(a[2]); r[3]=f2bs(a[3]);
  r[4]=f2bs(b[0]); r[5]=f2bs(b[1]); r[6]=f2bs(b[2]); r[7]=f2bs(b[3]);
  return r;
}

__device__ __forceinline__ void gload16(const void* g, void* l){
  __builtin_amdgcn_global_load_lds(
      (__attribute__((address_space(1))) void*)(g),
      (__attribute__((address_space(3))) void*)(l), 16, 0, 0);
}

// cast the 4 weight matrices (512x512 f32) to bf16 in one launch
__global__ __launch_bounds__(256) void cast_w(
    const float* __restrict__ w0, const float* __restrict__ w1,
    const float* __restrict__ w2, const float* __restrict__ w3,
    unsigned short* __restrict__ o0, unsigned short* __restrict__ o1,
    unsigned short* __restrict__ o2, unsigned short* __restrict__ o3)
{
  int g = blockIdx.x * 256 + threadIdx.x;
  int which = g >> 15;
  int off = (g & 32767) * 8;
  const float* src = which==0 ? w0 : which==1 ? w1 : which==2 ? w2 : w3;
  unsigned short* dst = which==0 ? o0 : which==1 ? o1 : which==2 ? o2 : o3;
  float4 a = *(const float4*)(src + off);
  float4 b = *(const float4*)(src + off + 4);
  u16x8 r;
  r[0]=f2bf(a.x); r[1]=f2bf(a.y); r[2]=f2bf(a.z); r[3]=f2bf(a.w);
  r[4]=f2bf(b.x); r[5]=f2bf(b.y); r[6]=f2bf(b.z); r[7]=f2bf(b.w);
  *(u16x8*)(dst + off) = r;
}

// Best-known engine (R13/R16): out[.][512] = (A_f32 @ B_bf16^T + bias)*scale
// BK=64, 2-slot dbuf, tile 128x256, 8 waves 2x4. One counted vmcnt per K-tile.
template<int OUT_MODE, int NT, int KT>
__global__ __launch_bounds__(512, 1) void gemm_k64(
    const float* __restrict__ A, const unsigned short* __restrict__ B,
    const float* __restrict__ bias, float scale, void* __restrict__ out_,
    int SA, int SB)
{
  __shared__ float          Af[2][128*64];
  __shared__ unsigned short Bf[2][256*64];

  const int nwg = gridDim.x;
  const int bid = blockIdx.x;
  const int wgid = (bid & 7) * (nwg >> 3) + (bid >> 3);

  const int t = threadIdx.x;
  const int wid = t >> 6, lane = t & 63;
  const int wm = wid >> 2, wn = wid & 3;
  const int rl = lane & 15, kg = lane >> 4;

  const int bn = wgid & 1;
  const int bmg = wgid >> 1;
  const float* Ab0 = A + (size_t)bmg * (NT*128) * SA;
  const unsigned short* Bb0 = B + (size_t)bn * 256 * SB;

  const int jrowA = wid*4 + (lane >> 4);
  const int aslot = lane & 15;
  const int jcolB = wid*8 + (lane >> 3);
  const int bslot = lane & 7;

  #define STAGE(T_) do{                                                        \
    const int st_ = (T_) & 1;                                                  \
    const int kt_ = (T_) & (KT-1);                                             \
    const int tau_ = (T_) / KT;                                                \
    const float* As_ = Ab0 + (size_t)tau_*128*SA + kt_*64;                     \
    const unsigned short* Bs_ = Bb0 + kt_*64;                                  \
    _Pragma("unroll")                                                          \
    for (int j = 0; j < 4; ++j){                                               \
      int ar = j*32 + jrowA;                                                   \
      gload16(As_ + (size_t)ar*SA + ((aslot ^ (ar&15)) << 2),                  \
              &Af[st_][(j*8 + wid)*256]);                                      \
      int bc = j*64 + jcolB;                                                   \
      gload16(Bs_ + (size_t)bc*SB + ((bslot ^ (bc&7)) << 3),                   \
              &Bf[st_][(j*8 + wid)*512]);                                      \
    }                                                                          \
  }while(0)

  #define READS(sl_, h_, af_, bw_) do{                                         \
    _Pragma("unroll")                                                          \
    for (int m = 0; m < 4; ++m){                                               \
      const int r_ = wm*64 + m*16 + rl;                                        \
      const int s0_ = (h_)*8 + kg*2;                                           \
      f32x4 x0 = *(const f32x4*)&Af[sl_][r_*64 + ((s0_     ^ (r_&15)) << 2)];  \
      f32x4 x1 = *(const f32x4*)&Af[sl_][r_*64 + (((s0_+1) ^ (r_&15)) << 2)];  \
      af_[m] = cvt8(x0, x1);                                                   \
    }                                                                          \
    _Pragma("unroll")                                                          \
    for (int n = 0; n < 4; ++n){                                               \
      const int c_ = wn*64 + n*16 + rl;                                        \
      const int sb_ = (h_)*4 + kg;                                             \
      bw_[n] = *(const s16x8*)&Bf[sl_][c_*64 + ((sb_ ^ (c_&7)) << 3)];         \
    }                                                                          \
  }while(0)

  #define MFMA16(af_, bw_) do{                                                 \
    __builtin_amdgcn_s_setprio(1);                                             \
    _Pragma("unroll")                                                          \
    for (int m = 0; m < 4; ++m)                                                \
      _Pragma("unroll")                                                        \
      for (int n = 0; n < 4; ++n)                                              \
        acc[m][n] = __builtin_amdgcn_mfma_f32_16x16x32_bf16(af_[m], bw_[n], acc[m][n], 0, 0, 0); \
    __builtin_amdgcn_s_setprio(0);                                             \
  }while(0)

  f32x4 acc[4][4];
  #pragma unroll
  for (int m=0;m<4;m++)
    #pragma unroll
    for (int n=0;n<4;n++) acc[m][n] = (f32x4){0.f,0.f,0.f,0.f};

  const int TT = NT * KT;
  STAGE(0); STAGE(1);
  asm volatile("s_waitcnt vmcnt(8)");
  __builtin_amdgcn_s_barrier();

  #pragma unroll 2
  for (int T = 0; T < TT; ++T){
    const int sl = T & 1;
    s16x8 af0[4], bw0[4], af1[4], bw1[4];

    READS(sl, 0, af0, bw0);
    MFMA16(af0, bw0);
    READS(sl, 1, af1, bw1);

    asm volatile("s_waitcnt lgkmcnt(0)");
    __builtin_amdgcn_s_barrier();

    if (T + 2 < TT) STAGE(T + 2);

    MFMA16(af1, bw1);

    if ((T & (KT-1)) == KT-1){
      const int tau = T / KT;
      #pragma unroll
      for (int n=0;n<4;n++){
        const int gcol = bn*256 + wn*64 + n*16 + rl;
        const float bv = bias[gcol];
        #pragma unroll
        for (int m=0;m<4;m++){
          #pragma unroll
          for (int r=0;r<4;r++){
            const int lrow = wm*64 + m*16 + kg*4 + r;
            const int grow = (bmg*NT + tau)*128 + lrow;
            float v = (acc[m][n][r] + bv) * scale;
            size_t idx = (size_t)grow * 512 + gcol;
            if (OUT_MODE == 1) ((unsigned short*)out_)[idx] = f2bf(v);
            else               ((float*)out_)[idx] = v;
          }
          acc[m][n] = (f32x4){0.f,0.f,0.f,0.f};
        }
      }
    }

    if (T + 2 < TT)      asm volatile("s_waitcnt vmcnt(8)");
    else if (T + 1 < TT) asm volatile("s_waitcnt vmcnt(0)");
    if (T + 1 < TT)      __builtin_amdgcn_s_barrier();
  }
  #undef STAGE
  #undef READS
  #undef MFMA16
}

// Fused K-proj -> scores (R19 + single-flush): Kp never materialized; K bias
// cancels. sc accumulates ALL 8 taus, one flush -> 256 slabs (34 MB part).
__global__ __launch_bounds__(512, 1) void gemm_ksc(
    const float* __restrict__ A, const unsigned short* __restrict__ B,
    const float* __restrict__ Qp, float* __restrict__ part)
{
  __shared__ float          Af[2][128*64];
  __shared__ unsigned short Bf[2][256*64];

  constexpr int NT = 8, KT = 8;
  const int nwg = gridDim.x;                    // 256
  const int bid = blockIdx.x;
  const int wgid = (bid & 7) * (nwg >> 3) + (bid >> 3);

  const int t = threadIdx.x;
  const int wid = t >> 6, lane = t & 63;
  const int wm = wid >> 2, wn = wid & 3;
  const int rl = lane & 15, kg = lane >> 4;

  const int bn = wgid & 1;
  const int bmg = wgid >> 1;
  const int b   = bmg >> 5;
  const int wwb = (bmg & 31) * 16;
  const float* Ab0 = A + (size_t)bmg * (NT*128) * 512;
  const unsigned short* Bb0 = B + (size_t)bn * 256 * 512;

  const int jrowA = wid*4 + (lane >> 4);
  const int aslot = lane & 15;
  const int jcolB = wid*8 + (lane >> 3);
  const int bslot = lane & 7;

  #define STAGE(T_) do{                                                        \
    const int st_ = (T_) & 1;                                                  \
    const int kt_ = (T_) & (KT-1);                                             \
    const int tau_ = (T_) / KT;                                                \
    const float* As_ = Ab0 + (size_t)tau_*128*512 + kt_*64;                    \
    const unsigned short* Bs_ = Bb0 + kt_*64;                                  \
    _Pragma("unroll")                                                          \
    for (int j = 0; j < 4; ++j){                                               \
      int ar = j*32 + jrowA;                                                   \
      gload16(As_ + (size_t)ar*512 + ((aslot ^ (ar&15)) << 2),                 \
              &Af[st_][(j*8 + wid)*256]);                                      \
      int bc = j*64 + jcolB;                                                   \
      gload16(Bs_ + (size_t)bc*512 + ((bslot ^ (bc&7)) << 3),                  \
              &Bf[st_][(j*8 + wid)*512]);                                      \
    }                                                                          \
  }while(0)

  #define READS(sl_, h_, af_, bw_) do{                                         \
    _Pragma("unroll")                                                          \
    for (int m = 0; m < 4; ++m){                                               \
      const int r_ = wm*64 + m*16 + rl;                                        \
      const int s0_ = (h_)*8 + kg*2;                                           \
      f32x4 x0 = *(const f32x4*)&Af[sl_][r_*64 + ((s0_     ^ (r_&15)) << 2)];  \
      f32x4 x1 = *(const f32x4*)&Af[sl_][r_*64 + (((s0_+1) ^ (r_&15)) << 2)];  \
      af_[m] = cvt8(x0, x1);                                                   \
    }                                                                          \
    _Pragma("unroll")                                                          \
    for (int n = 0; n < 4; ++n){                                               \
      const int c_ = wn*64 + n*16 + rl;                                        \
      const int sb_ = (h_)*4 + kg;                                             \
      bw_[n] = *(const s16x8*)&Bf[sl_][c_*64 + ((sb_ ^ (c_&7)) << 3)];         \
    }                                                                          \
  }while(0)

  #define MFMA16(af_, bw_) do{                                                 \
    __builtin_amdgcn_s_setprio(1);                                             \
    _Pragma("unroll")                                                          \
    for (int m = 0; m < 4; ++m)                                                \
      _Pragma("unroll")                                                        \
      for (int n = 0; n < 4; ++n)                                              \
        acc[m][n] = __builtin_amdgcn_mfma_f32_16x16x32_bf16(af_[m], bw_[n], acc[m][n], 0, 0, 0); \
    __builtin_amdgcn_s_setprio(0);                                             \
  }while(0)

  f32x4 acc[4][4], sc[4][4];
  #pragma unroll
  for (int m=0;m<4;m++)
    #pragma unroll
    for (int n=0;n<4;n++){
      acc[m][n] = (f32x4){0.f,0.f,0.f,0.f};
      sc[m][n]  = (f32x4){0.f,0.f,0.f,0.f};
    }
  float qp[4] = {0.f,0.f,0.f,0.f};

  const int TT = NT * KT;
  STAGE(0); STAGE(1);
  asm volatile("s_waitcnt vmcnt(8)");
  __builtin_amdgcn_s_barrier();

  #pragma unroll 2
  for (int T = 0; T < TT; ++T){
    const int sl = T & 1;
    s16x8 af0[4], bw0[4], af1[4], bw1[4];

    READS(sl, 0, af0, bw0);
    MFMA16(af0, bw0);
    READS(sl, 1, af1, bw1);

    asm volatile("s_waitcnt lgkmcnt(0)");
    __builtin_amdgcn_s_barrier();

    if (T + 2 < TT) STAGE(T + 2);

    if ((T & 7) == 0){
      const int tau = T >> 3;
      const int ww = wwb + tau*2 + wm;
      const float* qrow = Qp + ((size_t)(b*512 + ww))*512;
      #pragma unroll
      for (int n=0;n<4;n++) qp[n] = qrow[bn*256 + wn*64 + n*16 + rl];
    }

    MFMA16(af1, bw1);

    if ((T & 7) == 7){
      #pragma unroll
      for (int n=0;n<4;n++)
        #pragma unroll
        for (int m=0;m<4;m++){
          #pragma unroll
          for (int r=0;r<4;r++) sc[m][n][r] += qp[n] * acc[m][n][r];
          acc[m][n] = (f32x4){0.f,0.f,0.f,0.f};
        }
      if (T == TT-1){                      // single flush: 2 slabs per block
        const int s = b*64 + (bmg & 31)*2 + wm;
        #pragma unroll
        for (int n=0;n<4;n++){
          const int gcol = bn*256 + wn*64 + n*16 + rl;
          float* dst = part + ((size_t)s*512 + gcol)*64;
          #pragma unroll
          for (int m=0;m<4;m++)
            *(float4*)(dst + m*16 + kg*4) = *(float4*)&sc[m][n];
        }
      }
    }

    if (T + 2 < TT)      asm volatile("s_waitcnt vmcnt(8)");
    else if (T + 1 < TT) asm volatile("s_waitcnt vmcnt(0)");
    if (T + 1 < TT)      __builtin_amdgcn_s_barrier();
  }
  #undef STAGE
  #undef READS
  #undef MFMA16
}

// Fused PV v2 (R14/R16/R19, proven): att_out[(w*4+b)][dd] += sum_k V[b,w,k] *
// (attn[b,dd,k>>9]*Wvb[dd,k&511]). B rank-1, built in-kernel.
__global__ __launch_bounds__(512, 1) void gemm_pv2(
    const float* __restrict__ V, const unsigned short* __restrict__ Wvb,
    const float* __restrict__ attn, float* __restrict__ att_out)
{
  __shared__ float          Af[2][128*64];
  __shared__ unsigned short Bf[2][256*64];

  const int nwg = gridDim.x;                   // 256
  const int bid = blockIdx.x;
  const int wgid = (bid & 7) * (nwg >> 3) + (bid >> 3);
  const int bn = wgid & 1;
  const int mt = (wgid >> 1) & 3;
  const int b  = (wgid >> 3) & 3;
  const int sk = wgid >> 5;                    // k-chunk of 4096

  const int t = threadIdx.x;
  const int wid = t >> 6, lane = t & 63;
  const int wm = wid >> 2, wn = wid & 3;
  const int rl = lane & 15, kg = lane >> 4;

  const float* Ab0 = V + (size_t)b*512*32768 + (size_t)mt*128*32768 + (size_t)sk*4096;

  const int jrowA = wid*4 + (lane >> 4);
  const int aslot = lane & 15;

  const int colb = t >> 1, hb = t & 1;
  const unsigned short* Wrow = Wvb + (size_t)(bn*256 + colb)*512 + hb*32;
  const float* attn_row = attn + (size_t)(b*512 + bn*256 + colb)*64 + sk*8;

  s16x8 wv0_[4], wv1_[4];
  float at0_, at1_;

  #define STAGEA(T_) do{                                                       \
    const int st_ = (T_) & 1;                                                  \
    const float* As_ = Ab0 + (T_)*64;                                          \
    _Pragma("unroll")                                                          \
    for (int j = 0; j < 4; ++j){                                               \
      int ar = j*32 + jrowA;                                                   \
      gload16(As_ + (size_t)ar*32768 + ((aslot ^ (ar&15)) << 2),               \
              &Af[st_][(j*8 + wid)*256]);                                      \
    }                                                                          \
  }while(0)

  #define BLOAD0(T_) do{ const unsigned short* w_ = Wrow + ((T_)&7)*64;        \
    wv0_[0]=*(const s16x8*)(w_);    wv0_[1]=*(const s16x8*)(w_+8);             \
    wv0_[2]=*(const s16x8*)(w_+16); wv0_[3]=*(const s16x8*)(w_+24);            \
    at0_ = attn_row[(T_)>>3]; }while(0)
  #define BLOAD1(T_) do{ const unsigned short* w_ = Wrow + ((T_)&7)*64;        \
    wv1_[0]=*(const s16x8*)(w_);    wv1_[1]=*(const s16x8*)(w_+8);             \
    wv1_[2]=*(const s16x8*)(w_+16); wv1_[3]=*(const s16x8*)(w_+24);            \
    at1_ = attn_row[(T_)>>3]; }while(0)

  #define BWRITE0() do{ unsigned short* d_ = &Bf[0][colb*64];                  \
    _Pragma("unroll") for (int q=0;q<4;++q){ s16x8 o8;                         \
      _Pragma("unroll") for (int j=0;j<8;++j)                                  \
        o8[j] = f2bs(bf2f((unsigned short)wv0_[q][j]) * at0_);                 \
      *(s16x8*)(d_ + (((hb*4+q) ^ (colb&7)) << 3)) = o8; } }while(0)
  #define BWRITE1() do{ unsigned short* d_ = &Bf[1][colb*64];                  \
    _Pragma("unroll") for (int q=0;q<4;++q){ s16x8 o8;                         \
      _Pragma("unroll") for (int j=0;j<8;++j)                                  \
        o8[j] = f2bs(bf2f((unsigned short)wv1_[q][j]) * at1_);                 \
      *(s16x8*)(d_ + (((hb*4+q) ^ (colb&7)) << 3)) = o8; } }while(0)

  #define READS(sl_, h_, af_, bw_) do{                                         \
    _Pragma("unroll")                                                          \
    for (int m = 0; m < 4; ++m){                                               \
      const int r_ = wm*64 + m*16 + rl;                                        \
      const int s0_ = (h_)*8 + kg*2;                                           \
      f32x4 x0 = *(const f32x4*)&Af[sl_][r_*64 + ((s0_     ^ (r_&15)) << 2)];  \
      f32x4 x1 = *(const f32x4*)&Af[sl_][r_*64 + (((s0_+1) ^ (r_&15)) << 2)];  \
      af_[m] = cvt8(x0, x1);                                                   \
    }                                                                          \
    _Pragma("unroll")                                                          \
    for (int n = 0; n < 4; ++n){                                               \
      const int c_ = wn*64 + n*16 + rl;                                        \
      const int sb_ = (h_)*4 + kg;                                             \
      bw_[n] = *(const s16x8*)&Bf[sl_][c_*64 + ((sb_ ^ (c_&7)) << 3)];         \
    }                                                                          \
  }while(0)

  #define MFMA16(af_, bw_) do{                                                 \
    __builtin_amdgcn_s_setprio(1);                                             \
    _Pragma("unroll")                                                          \
    for (int m = 0; m < 4; ++m)                                                \
      _Pragma("unroll")                                                        \
      for (int n = 0; n < 4; ++n)                                              \
        acc[m][n] = __builtin_amdgcn_mfma_f32_16x16x32_bf16(af_[m], bw_[n], acc[m][n], 0, 0, 0); \
    __builtin_amdgcn_s_setprio(0);                                             \
  }while(0)

  f32x4 acc[4][4];
  #pragma unroll
  for (int m=0;m<4;m++)
    #pragma unroll
    for (int n=0;n<4;n++) acc[m][n] = (f32x4){0.f,0.f,0.f,0.f};

  STAGEA(0); BLOAD0(0);
  STAGEA(1); BLOAD1(1);
  BWRITE0();
  asm volatile("s_waitcnt lgkmcnt(0)");
  asm volatile("s_waitcnt vmcnt(9)");
  __builtin_amdgcn_s_barrier();

  #pragma unroll 2
  for (int T = 0; T < 64; ++T){
    const int sl = T & 1;
    s16x8 af0[4], bw0[4], af1[4], bw1[4];

    READS(sl, 0, af0, bw0);
    MFMA16(af0, bw0);
    READS(sl, 1, af1, bw1);

    asm volatile("s_waitcnt lgkmcnt(0)");
    __builtin_amdgcn_s_barrier();

    if (T + 2 < 64){
      STAGEA(T + 2);
      if (((T+2)&1)==0) BLOAD0(T+2); else BLOAD1(T+2);
    }
    if (T + 1 < 64){
      if (((T+1)&1)==0) BWRITE0(); else BWRITE1();
    }

    MFMA16(af1, bw1);

    if (T == 63){
      #pragma unroll
      for (int n=0;n<4;n++){
        const int gcol = bn*256 + wn*64 + n*16 + rl;
        #pragma unroll
        for (int m=0;m<4;m++)
          #pragma unroll
          for (int r=0;r<4;r++){
            const int lrow = wm*64 + m*16 + kg*4 + r;
            const int w_ = mt*128 + lrow;
            atomicAdd(&att_out[(size_t)(w_*4 + b)*512 + gcol], acc[m][n][r]);
          }
      }
    }

    if (T + 1 < 64){
      asm volatile("s_waitcnt lgkmcnt(0)");
      if (T + 2 < 64) asm volatile("s_waitcnt vmcnt(9)");
      else            asm volatile("s_waitcnt vmcnt(0)");
      __builtin_amdgcn_s_barrier();
    }
  }
  #undef STAGEA
  #undef BLOAD0
  #undef BLOAD1
  #undef BWRITE0
  #undef BWRITE1
  #undef READS
  #undef MFMA16
}

// softmax over m (reducing 64 slabs/row) + fused att_out bias-init
__global__ __launch_bounds__(256) void softmax_kernel(
    const float* __restrict__ part, float* __restrict__ attn,
    const float* __restrict__ bv, float* __restrict__ att_out)
{
  const int row = blockIdx.x*4 + (threadIdx.x >> 6);  // b*512+dd, 0..2047
  const int m = threadIdx.x & 63;
  const int b = row >> 9, dd = row & 511;
  float v = 0.f;
  #pragma unroll 8
  for (int j = 0; j < 64; ++j)
    v += part[((size_t)(b*64 + j)*512 + dd)*64 + m];
  float mx = v;
  #pragma unroll
  for (int o=32;o>=1;o>>=1) mx = fmaxf(mx, __shfl_xor(mx, o));
  float e = __expf(v - mx);
  float s = e;
  #pragma unroll
  for (int o=32;o>=1;o>>=1) s += __shfl_xor(s, o);
  attn[(size_t)row*64 + m] = e / s;

  const int base = blockIdx.x*256 + threadIdx.x;
  #pragma unroll
  for (int i=0;i<8;i++){
    int el = base + i*131072;
    att_out[el] = bv[el & 511];
  }
}

extern "C" void kernel_launch(void* const* d_in, const int* in_sizes, int n_in,
                              void* d_out, int out_size, void* d_ws, size_t ws_size,
                              hipStream_t stream) {
  const float* Q  = (const float*)d_in[0];
  const float* K  = (const float*)d_in[1];
  const float* V  = (const float*)d_in[2];
  const float* Wq = (const float*)d_in[3];
  const float* bq = (const float*)d_in[4];
  const float* Wk = (const float*)d_in[5];
  const float* bk = (const float*)d_in[6];
  const float* Wv = (const float*)d_in[7];
  const float* bv = (const float*)d_in[8];
  const float* Wp = (const float*)d_in[9];
  const float* bp = (const float*)d_in[10];
  float* out = (float*)d_out;
  (void)bk;  // K bias cancels in softmax

  char* ws = (char*)d_ws;
  float* Qp       = (float*)(ws);                       // 4 MiB
  float* att_out  = (float*)(ws + ((size_t)4<<20));     // 4 MiB
  float* attn     = (float*)(ws + ((size_t)8<<20));     // 0.5 MiB
  unsigned short* Wqb = (unsigned short*)(ws + ((size_t)9<<20));
  unsigned short* Wkb = Wqb + 262144;
  unsigned short* Wvb = Wkb + 262144;
  unsigned short* Wpb = Wvb + 262144;                   // 2 MiB total
  float* part     = (float*)(ws + ((size_t)11<<20));    // 256x512x64 f32 = 34 MiB

  const float qscale = 0.044194173824159223f;  // 1/sqrt(512)

  cast_w<<<512, 256, 0, stream>>>(Wq, Wk, Wv, Wp, Wqb, Wkb, Wvb, Wpb);

  // Q projection (+bias, /sqrt(d)) -> f32
  gemm_k64<0,1,8><<<32, 512, 0, stream>>>(Q, Wqb, bq, qscale, Qp, 512, 512);
  // fused K-projection -> score partials (single flush, 256 slabs)
  gemm_ksc<<<256, 512, 0, stream>>>(K, Wkb, Qp, part);
  // softmax (64-slab reduce) + att_out bias-init
  softmax_kernel<<<512, 256, 0, stream>>>(part, attn, bv, att_out);
  // fused PV: att_out += V @ (attn x Wvb)^T, B built in-kernel
  gemm_pv2<<<256, 512, 0, stream>>>(V, Wvb, attn, att_out);
  // output projection -> d_out
  gemm_k64<0,1,8><<<32, 512, 0, stream>>>(att_out, Wpb, bp, 1.f, out, 512, 512);
}